// Round 1
// baseline (116.260 us; speedup 1.0000x reference)
//
#include <hip/hip_runtime.h>
#include <math.h>

// SchurDecompositionLinear collapses algebraically:
//   apply_P right-multiplies by Q = H0*H1*...*H{n-1} (orthogonal, symmetric Hi)
//   W = (T*Q)*(I*Q)^T = T*Q*Q^T = T  (exact)
// T is block-diagonal 2x2: [[c,-s],[s,c]] * gamma per pair.
// So out = x @ T is an elementwise pairwise rotation — memory-bound.

#define NCOLS 256
#define NPAIR (NCOLS / 2)   // 128
#define F4_PER_ROW (NCOLS / 4)  // 64

__global__ __launch_bounds__(256) void schur_rot_kernel(
    const float4* __restrict__ x4,
    const float* __restrict__ theta,
    const float* __restrict__ gamma,
    float4* __restrict__ out4,
    int total4)
{
    __shared__ float sc[NPAIR];
    __shared__ float ss[NPAIR];

    int t = threadIdx.x;
    if (t < NPAIR) {
        float th = theta[t];
        float g  = gamma[t];
        sc[t] = g * cosf(th);
        ss[t] = g * sinf(th);
    }
    __syncthreads();

    int idx = blockIdx.x * blockDim.x + t;
    if (idx >= total4) return;

    int col4 = idx & (F4_PER_ROW - 1);      // which float4 within the row
    int k0 = 2 * col4;                      // pair index for (.x,.y)
    float c0 = sc[k0],     s0 = ss[k0];
    float c1 = sc[k0 + 1], s1 = ss[k0 + 1];

    float4 v = x4[idx];
    float4 o;
    o.x = c0 * v.x + s0 * v.y;
    o.y = c0 * v.y - s0 * v.x;
    o.z = c1 * v.z + s1 * v.w;
    o.w = c1 * v.w - s1 * v.z;
    out4[idx] = o;
}

extern "C" void kernel_launch(void* const* d_in, const int* in_sizes, int n_in,
                              void* d_out, int out_size, void* d_ws, size_t ws_size,
                              hipStream_t stream) {
    const float* x     = (const float*)d_in[0];   // [rows, 256]
    // d_in[1] = U  — unused: it cancels exactly (Q*Q^T = I)
    const float* theta = (const float*)d_in[2];   // [128]
    const float* gamma = (const float*)d_in[3];   // [128]
    float* out = (float*)d_out;

    int total  = in_sizes[0];          // rows * 256
    int total4 = total / 4;            // float4 count

    int block = 256;
    int grid  = (total4 + block - 1) / block;

    schur_rot_kernel<<<grid, block, 0, stream>>>(
        (const float4*)x, theta, gamma, (float4*)out, total4);
}